// Round 6
// baseline (330.888 us; speedup 1.0000x reference)
//
#include <hip/hip_runtime.h>
#include <hip/hip_bf16.h>

#define VOCAB 100000
#define EMBED 64
#define SENT  20
#define MEM   50
#define BATCH 32
#define HOPS  3

// 4 gather sets: t=0 -> A (m for hop0); t=1..3 -> C[t-1] (c for hop t-1, m for hop t).
// Exploits m_h == c_{h-1} (same table, same words, same encoding).
#define NSET  4
#define NSLOT (NSET * BATCH * MEM)   // 6400
#define NVT   (VOCAB / 16)           // 6250 vocab tiles (exact)
#define PERB  (NSET * MEM + 1)       // 201 contributions per batch (200 sent + 1 query)

typedef __attribute__((ext_vector_type(8))) short short8v;  // 8 bf16 = 4 VGPR
typedef __attribute__((ext_vector_type(4))) float f32x4;

__device__ __forceinline__ float bfr(unsigned short x) {
    union { unsigned int u; float f; } cv;
    cv.u = ((unsigned int)x) << 16;
    return cv.f;
}

// Runtime dtype probe: enc row 19 (last) is exactly 1.0 everywhere.
// bf16 storage: dword 639 packs elements 1278,1279 = (1.0bf,1.0bf) = 0x3F803F80.
__device__ __forceinline__ bool is_bf16(const void* enc) {
    return ((const unsigned int*)enc)[639] == 0x3F803F80u;
}

template<bool BF>
__device__ __forceinline__ float ldT(const void* p, size_t idx) {
    if constexpr (BF) return bfr(((const unsigned short*)p)[idx]);
    else              return ((const float*)p)[idx];
}

__device__ __forceinline__ float wave_sum(float d) {
#pragma unroll
    for (int off = 32; off > 0; off >>= 1) d += __shfl_xor(d, off, 64);
    return d;
}

// ---- 3-hop recurrence for one batch, whole block (4 waves), reads mc_ws
// straight from L2 (R3-phase2-proven). uls[64], ols[256] in LDS. ----
__device__ void recur_one(const float* __restrict__ mc_ws,
                          const float* __restrict__ u0g,
                          float* __restrict__ u3g,
                          unsigned short* __restrict__ u3bf,
                          float* __restrict__ uls,
                          float* __restrict__ ols,
                          int b)
{
    const int tid  = threadIdx.x;
    const int lane = tid & 63;
    const int widx = tid >> 6;

    if (tid < EMBED) uls[tid] = u0g[b * EMBED + tid];
    __syncthreads();

    for (int hop = 0; hop < HOPS; ++hop) {
        // dot: lane mm computes <m[mm], u> (all 4 waves redundantly)
        float d = 0.f;
        if (lane < MEM) {
            const float* row = mc_ws +
                ((size_t)hop * BATCH * MEM + (size_t)b * MEM + lane) * EMBED;
#pragma unroll
            for (int e2 = 0; e2 < EMBED; ++e2) d += row[e2] * uls[e2];
        }
        // softmax over lanes 0..49 (in-lane, per wave)
        float x  = (lane < MEM) ? d : -3.4e38f;
        float mx = x;
#pragma unroll
        for (int off = 32; off > 0; off >>= 1) mx = fmaxf(mx, __shfl_xor(mx, off, 64));
        float ex = (lane < MEM) ? __expf(x - mx) : 0.f;
        float sm = wave_sum(ex);
        float p  = ex / sm;

        // weighted sum: wave w covers mm = 13w .. 13w+12 (w3: 39..49)
        float o = 0.f;
        const float* crow = mc_ws +
            ((size_t)(hop + 1) * BATCH * MEM + (size_t)b * MEM) * EMBED;
#pragma unroll
        for (int k = 0; k < 13; ++k) {
            int mm = widx * 13 + k;
            if (mm < MEM)
                o += __shfl(p, mm, 64) * crow[mm * EMBED + lane];
        }
        ols[widx * EMBED + lane] = o;
        __syncthreads();
        if (tid < EMBED)
            uls[tid] += ols[0*EMBED+tid] + ols[1*EMBED+tid]
                      + ols[2*EMBED+tid] + ols[3*EMBED+tid];
        __syncthreads();
    }

    if (tid < EMBED) {
        float uv = uls[tid];
        u3g[b * EMBED + tid] = uv;
        __hip_bfloat16 h = __float2bfloat16(uv);
        u3bf[b * EMBED + tid] = *(unsigned short*)&h;
    }
    __syncthreads();   // protect uls/ols reuse if this block finishes 2 batches
}

// ---- gather body, dtype hoisted: one slot per wave; returns this wave's batch ----
template<bool BF>
__device__ __forceinline__ int gather_body(const int* __restrict__ stories,
                                           const int* __restrict__ queries,
                                           const void* __restrict__ A,
                                           const void* __restrict__ C,
                                           const void* __restrict__ enc,
                                           float* __restrict__ mc_ws,
                                           float* __restrict__ u0g)
{
    const int tid = threadIdx.x;
    const int e   = tid & 63;
    const int gw  = blockIdx.x * 4 + (tid >> 6);
    const size_t VE = (size_t)VOCAB * EMBED;

    float encr[SENT];
#pragma unroll
    for (int s = 0; s < SENT; ++s) encr[s] = ldT<BF>(enc, s * EMBED + e);

    if (gw < NSLOT) {
        const int t  = gw / (BATCH * MEM);
        const int bm = gw % (BATCH * MEM);
        const void* T   = (t == 0) ? A : C;
        const size_t to = (t == 0) ? 0 : (size_t)(t - 1) * VE;

        int wst = (e < SENT) ? stories[bm * SENT + e] : 0;
        float acc = 0.f;
#pragma unroll
        for (int s = 0; s < SENT; ++s) {
            int w = __shfl(wst, s, 64);
            acc += ldT<BF>(T, to + (size_t)w * EMBED + e) * encr[s];
        }
        mc_ws[gw * EMBED + e] = acc;
        return bm / MEM;                  // batch of this sentence slot
    } else {
        const int b = gw - NSLOT;         // gw in [6400,6432): query slot
        int wq = (e < SENT) ? queries[b * SENT + e] : 0;
        float u = 0.f;
#pragma unroll
        for (int s = 0; s < SENT; ++s) {
            int w = __shfl(wq, s, 64);
            u += ldT<BF>(A, (size_t)w * EMBED + e) * encr[s];
        }
        u0g[b * EMBED + e] = u;
        return b;
    }
}

// ---- Kernel 1: wide gather + per-batch last-arrival inline recurrence.
// No spinning (deadlock-impossible): each wave bumps cnt[b] with an
// acq_rel agent-scope add; the 201st arrival's block runs batch b's
// recurrence (acquire side makes all contributors' stores visible;
// L1 invalidate is CU-wide so the whole block sees them post-barrier).
__global__ __launch_bounds__(256) void k_gather_recur(
    const int* __restrict__ stories,   // [32,50,20]
    const int* __restrict__ queries,   // [32,20]
    const void* __restrict__ A,        // [V,64]
    const void* __restrict__ C,        // [3,V,64]
    const void* __restrict__ enc,      // [20,64]
    float* __restrict__ mc_ws,         // [6400,64]
    float* __restrict__ u0g,           // [32,64]
    float* __restrict__ u3g,           // [32,64]
    unsigned short* __restrict__ u3bf, // [32,64] bf16
    unsigned* __restrict__ cnt)        // [32], pre-zeroed
{
    __shared__ float uls[EMBED];
    __shared__ float ols[4 * EMBED];
    __shared__ int   finishb[4];

    const int tid  = threadIdx.x;
    const int lane = tid & 63;
    const int widx = tid >> 6;

    int b;
    if (is_bf16(enc)) b = gather_body<true >(stories, queries, A, C, enc, mc_ws, u0g);
    else              b = gather_body<false>(stories, queries, A, C, enc, mc_ws, u0g);

    // one atomic per wave; finisher detection on lane 0
    if (lane == 0) {
        unsigned old = __hip_atomic_fetch_add(&cnt[b], 1u, __ATOMIC_ACQ_REL,
                                              __HIP_MEMORY_SCOPE_AGENT);
        finishb[widx] = (old == (unsigned)(PERB - 1)) ? b : -1;
    }
    __syncthreads();

#pragma unroll
    for (int w = 0; w < 4; ++w) {
        const int fb = finishb[w];        // uniform across block
        if (fb >= 0)
            recur_one(mc_ws, u0g, u3g, u3bf, uls, ols, fb);
    }
}

// ---- k_out fp32 fallback: R0-proven LDS-staged per-thread dot ----
__device__ __forceinline__ void out_f32(const float* __restrict__ u,
                                        const void* __restrict__ Cbase,
                                        void* __restrict__ out)
{
    if (blockIdx.x * 256 >= VOCAB) return;
    __shared__ __align__(16) float su[BATCH * EMBED];
    for (int i = threadIdx.x; i < BATCH * EMBED; i += 256) su[i] = u[i];
    __syncthreads();
    const int v = blockIdx.x * 256 + threadIdx.x;
    if (v >= VOCAB) return;

    const size_t c2_off = (size_t)2 * VOCAB * EMBED;
    float row[EMBED];
    const float4* rp = (const float4*)((const float*)Cbase + c2_off + (size_t)v * EMBED);
#pragma unroll
    for (int i = 0; i < 16; ++i) {
        float4 r = rp[i];
        row[i*4 + 0] = r.x; row[i*4 + 1] = r.y;
        row[i*4 + 2] = r.z; row[i*4 + 3] = r.w;
    }

    float* of = (float*)out;
#pragma unroll
    for (int bb = 0; bb < BATCH; ++bb) {
        const float4* sp = (const float4*)(su + bb * EMBED);
        float acc = 0.f;
#pragma unroll
        for (int e4 = 0; e4 < 16; ++e4) {
            float4 us = sp[e4];
            acc += row[e4*4+0]*us.x + row[e4*4+1]*us.y
                 + row[e4*4+2]*us.z + row[e4*4+3]*us.w;
        }
        of[(size_t)bb * VOCAB + v] = acc;
    }
}

// ---- k_out bf16: MFMA tile GEMM  out[32 x 100000] = u3bf[32x64] . C2^T ----
// [R5-proven] One wave per 16-column vocab tile. mfma_f32_16x16x32_bf16:
//   A frag: lane holds A[lane&15][(lane>>4)*8 .. +8)   (16B contiguous)
//   B frag: lane holds C2[vt*16+(lane&15)][(lane>>4)*8 .. +8)
//   D frag: col=lane&15, row=(lane>>4)*4+j   [m89-verified]
__device__ __forceinline__ void out_mfma(const unsigned short* __restrict__ ubf,
                                         const void* __restrict__ Cbase,
                                         void* __restrict__ out)
{
    const int tid  = threadIdx.x;
    const int tv   = blockIdx.x * 4 + (tid >> 6);
    if (tv >= NVT) return;
    const int lane = tid & 63;
    const int l15  = lane & 15;
    const int lh   = lane >> 4;

    const unsigned short* c2 =
        (const unsigned short*)Cbase + (size_t)2 * VOCAB * EMBED;

    const short8v a00 = *(const short8v*)(ubf + ( 0 + l15) * EMBED +  0 + lh * 8);
    const short8v a01 = *(const short8v*)(ubf + ( 0 + l15) * EMBED + 32 + lh * 8);
    const short8v a10 = *(const short8v*)(ubf + (16 + l15) * EMBED +  0 + lh * 8);
    const short8v a11 = *(const short8v*)(ubf + (16 + l15) * EMBED + 32 + lh * 8);

    const unsigned short* brow = c2 + ((size_t)tv * 16 + l15) * EMBED + lh * 8;
    const short8v b0 = *(const short8v*)(brow);
    const short8v b1 = *(const short8v*)(brow + 32);

    f32x4 acc0 = {0.f, 0.f, 0.f, 0.f};
    f32x4 acc1 = {0.f, 0.f, 0.f, 0.f};
    acc0 = __builtin_amdgcn_mfma_f32_16x16x32_bf16(a00, b0, acc0, 0, 0, 0);
    acc0 = __builtin_amdgcn_mfma_f32_16x16x32_bf16(a01, b1, acc0, 0, 0, 0);
    acc1 = __builtin_amdgcn_mfma_f32_16x16x32_bf16(a10, b0, acc1, 0, 0, 0);
    acc1 = __builtin_amdgcn_mfma_f32_16x16x32_bf16(a11, b1, acc1, 0, 0, 0);

    unsigned short* ob = (unsigned short*)out;
    const int v = tv * 16 + l15;
#pragma unroll
    for (int j = 0; j < 4; ++j) {
        const int br = lh * 4 + j;
        __hip_bfloat16 h0 = __float2bfloat16(acc0[j]);
        ob[(size_t)br * VOCAB + v] = *(unsigned short*)&h0;
        __hip_bfloat16 h1 = __float2bfloat16(acc1[j]);
        ob[(size_t)(16 + br) * VOCAB + v] = *(unsigned short*)&h1;
    }
}

__global__ __launch_bounds__(256) void k_out(const float* __restrict__ u,
                                             const unsigned short* __restrict__ ubf,
                                             const void* __restrict__ Cbase,
                                             const void* __restrict__ enc,
                                             void* __restrict__ out)
{
    if (is_bf16(enc)) out_mfma(ubf, Cbase, out);
    else              out_f32(u, Cbase, out);
}

extern "C" void kernel_launch(void* const* d_in, const int* in_sizes, int n_in,
                              void* d_out, int out_size, void* d_ws, size_t ws_size,
                              hipStream_t stream)
{
    const int*  stories = (const int*)d_in[0];
    const int*  queries = (const int*)d_in[1];
    const void* A       = d_in[2];
    const void* C       = d_in[3];
    const void* enc     = d_in[4];

    float* mc_ws = (float*)d_ws;                 // [6400,64] f32
    float* u0g   = mc_ws + NSLOT * EMBED;        // [32,64] f32
    float* u3g   = u0g + BATCH * EMBED;          // [32,64] f32
    unsigned short* u3bf = (unsigned short*)(u3g + BATCH * EMBED);  // [32,64] bf16
    unsigned* cnt = (unsigned*)(u3bf + BATCH * EMBED);              // [32]

    const int nblocks = (NSLOT + BATCH) / 4;     // 1608
    const int noutblk = (NVT + 3) / 4;           // 1563

    // workspace is poisoned between iterations -> zero the 128 B counter array
    hipMemsetAsync(cnt, 0, BATCH * sizeof(unsigned), stream);

    k_gather_recur<<<nblocks, 256, 0, stream>>>(stories, queries, A, C, enc,
                                                mc_ws, u0g, u3g, u3bf, cnt);
    k_out<<<noutblk, 256, 0, stream>>>(u3g, u3bf, C, enc, d_out);
}

// Round 7
// 270.834 us; speedup vs baseline: 1.2217x; 1.2217x over previous
//
#include <hip/hip_runtime.h>
#include <hip/hip_bf16.h>

#define VOCAB 100000
#define EMBED 64
#define SENT  20
#define MEM   50
#define BATCH 32
#define HOPS  3

// 4 gather sets: t=0 -> A (m for hop0); t=1..3 -> C[t-1] (c for hop t-1, m for hop t).
// Exploits m_h == c_{h-1} (same table, same words, same encoding).
#define NSET  4
#define NSLOT (NSET * BATCH * MEM)   // 6400
#define NVT   (VOCAB / 16)           // 6250 vocab tiles (exact)
#define NOUTB ((NVT + 3) / 4)        // 1563 blocks for k_out2

typedef __attribute__((ext_vector_type(8))) short short8v;  // 8 bf16 = 4 VGPR
typedef __attribute__((ext_vector_type(4))) float f32x4;

__device__ __forceinline__ float bfr(unsigned short x) {
    union { unsigned int u; float f; } cv;
    cv.u = ((unsigned int)x) << 16;
    return cv.f;
}

// Runtime dtype probe: enc row 19 (last) is exactly 1.0 everywhere.
// bf16 storage: dword 639 packs elements 1278,1279 = (1.0bf,1.0bf) = 0x3F803F80.
__device__ __forceinline__ bool is_bf16(const void* enc) {
    return ((const unsigned int*)enc)[639] == 0x3F803F80u;
}

template<bool BF>
__device__ __forceinline__ float ldT(const void* p, size_t idx) {
    if constexpr (BF) return bfr(((const unsigned short*)p)[idx]);
    else              return ((const float*)p)[idx];
}

__device__ __forceinline__ float wave_sum(float d) {
#pragma unroll
    for (int off = 32; off > 0; off >>= 1) d += __shfl_xor(d, off, 64);
    return d;
}

// ---- gather body, dtype hoisted: one slot per wave (full-width, 6432 waves) ----
template<bool BF>
__device__ __forceinline__ void gather_body(const int* __restrict__ stories,
                                            const int* __restrict__ queries,
                                            const void* __restrict__ A,
                                            const void* __restrict__ C,
                                            const void* __restrict__ enc,
                                            float* __restrict__ mc_ws,
                                            float* __restrict__ u0g)
{
    const int tid = threadIdx.x;
    const int e   = tid & 63;
    const int gw  = blockIdx.x * 4 + (tid >> 6);
    const size_t VE = (size_t)VOCAB * EMBED;

    float encr[SENT];
#pragma unroll
    for (int s = 0; s < SENT; ++s) encr[s] = ldT<BF>(enc, s * EMBED + e);

    if (gw < NSLOT) {
        const int t  = gw / (BATCH * MEM);
        const int bm = gw % (BATCH * MEM);
        const void* T   = (t == 0) ? A : C;
        const size_t to = (t == 0) ? 0 : (size_t)(t - 1) * VE;

        int wst = (e < SENT) ? stories[bm * SENT + e] : 0;
        float acc = 0.f;
#pragma unroll
        for (int s = 0; s < SENT; ++s) {
            int w = __shfl(wst, s, 64);
            acc += ldT<BF>(T, to + (size_t)w * EMBED + e) * encr[s];
        }
        mc_ws[gw * EMBED + e] = acc;
    } else if (gw < NSLOT + BATCH) {
        const int b = gw - NSLOT;
        int wq = (e < SENT) ? queries[b * SENT + e] : 0;
        float u = 0.f;
#pragma unroll
        for (int s = 0; s < SENT; ++s) {
            int w = __shfl(wq, s, 64);
            u += ldT<BF>(A, (size_t)w * EMBED + e) * encr[s];
        }
        u0g[b * EMBED + e] = u;
    }
}

__global__ __launch_bounds__(256) void k_gather(
    const int* __restrict__ stories,   // [32,50,20]
    const int* __restrict__ queries,   // [32,20]
    const void* __restrict__ A,        // [V,64]
    const void* __restrict__ C,        // [3,V,64]
    const void* __restrict__ enc,      // [20,64]
    float* __restrict__ mc_ws,         // [6400,64]
    float* __restrict__ u0g)           // [32,64]
{
    if (is_bf16(enc)) gather_body<true >(stories, queries, A, C, enc, mc_ws, u0g);
    else              gather_body<false>(stories, queries, A, C, enc, mc_ws, u0g);
}

// ---- 3-hop recurrence for one batch (4 waves), mc_ws read from L2.
// [R3-phase2 / R6 correctness-proven verbatim] ----
__device__ void recur_global(const float* __restrict__ mc_ws,
                             const float* __restrict__ u0g,
                             float* __restrict__ u3g,
                             unsigned short* __restrict__ u3bf,
                             float* __restrict__ uls,
                             float* __restrict__ ols,
                             int b)
{
    const int tid  = threadIdx.x;
    const int lane = tid & 63;
    const int widx = tid >> 6;

    if (tid < EMBED) uls[tid] = u0g[b * EMBED + tid];
    __syncthreads();

    for (int hop = 0; hop < HOPS; ++hop) {
        float d = 0.f;
        if (lane < MEM) {
            const float* row = mc_ws +
                ((size_t)hop * BATCH * MEM + (size_t)b * MEM + lane) * EMBED;
#pragma unroll
            for (int e2 = 0; e2 < EMBED; ++e2) d += row[e2] * uls[e2];
        }
        float x  = (lane < MEM) ? d : -3.4e38f;
        float mx = x;
#pragma unroll
        for (int off = 32; off > 0; off >>= 1) mx = fmaxf(mx, __shfl_xor(mx, off, 64));
        float ex = (lane < MEM) ? __expf(x - mx) : 0.f;
        float sm = wave_sum(ex);
        float p  = ex / sm;

        float o = 0.f;
        const float* crow = mc_ws +
            ((size_t)(hop + 1) * BATCH * MEM + (size_t)b * MEM) * EMBED;
#pragma unroll
        for (int k = 0; k < 13; ++k) {
            int mm = widx * 13 + k;
            if (mm < MEM)
                o += __shfl(p, mm, 64) * crow[mm * EMBED + lane];
        }
        ols[widx * EMBED + lane] = o;
        __syncthreads();
        if (tid < EMBED)
            uls[tid] += ols[0*EMBED+tid] + ols[1*EMBED+tid]
                      + ols[2*EMBED+tid] + ols[3*EMBED+tid];
        __syncthreads();
    }

    // NOTE: u3g/u3bf stores all come from wave 0 (tid<64) — same wave as the
    // release-add below, so the release fence covers them.
    if (tid < EMBED) {
        float uv = uls[tid];
        u3g[b * EMBED + tid] = uv;
        __hip_bfloat16 h = __float2bfloat16(uv);
        u3bf[b * EMBED + tid] = *(unsigned short*)&h;
    }
}

// ---- Kernel 2: fused recurrence(32 producer blocks) + output GEMM ----
// Liveness without dispatch-order assumptions: launch_bounds(256,8) caps
// VGPR<=64 -> 8 blocks/CU -> capacity 2048 >= 1563 -> ALL blocks (incl. all
// 32 producers) co-resident. Sync cost: 32 release RMWs + sleepy polls
// (R6 lesson: thousands of acq_rel RMWs = 30ns each; 32 is negligible).
__global__ __launch_bounds__(256, 8) void k_out2(
    const float* __restrict__ mc_ws,
    const float* __restrict__ u0g,
    float* __restrict__ u3g,
    unsigned short* __restrict__ u3bf,
    unsigned* __restrict__ done,       // pre-zeroed, own cache line
    const void* __restrict__ Cbase,
    const void* __restrict__ enc,
    void* __restrict__ out)
{
    __shared__ float uls[EMBED];
    __shared__ float ols[4 * EMBED];
    __shared__ __align__(16) float su[BATCH * EMBED];

    const int tid  = threadIdx.x;
    const bool bf  = is_bf16(enc);
    const int lane = tid & 63;
    const int l15  = lane & 15;
    const int lh   = lane >> 4;
    const int tv   = blockIdx.x * 4 + (tid >> 6);

    // --- prefetch this wave's C2 B-frags (independent of u3) ---
    short8v b0 = {}, b1 = {};
    const unsigned short* c2 =
        (const unsigned short*)Cbase + (size_t)2 * VOCAB * EMBED;
    if (bf && tv < NVT) {
        const unsigned short* brow = c2 + ((size_t)tv * 16 + l15) * EMBED + lh * 8;
        b0 = *(const short8v*)(brow);
        b1 = *(const short8v*)(brow + 32);
    }

    // --- producers: blocks 0..31 compute batch b's recurrence ---
    if (blockIdx.x < BATCH) {
        recur_global(mc_ws, u0g, u3g, u3bf, uls, ols, blockIdx.x);
        __syncthreads();
        if (tid == 0)
            __hip_atomic_fetch_add(done, 1u, __ATOMIC_RELEASE,
                                   __HIP_MEMORY_SCOPE_AGENT);
    }

    // --- everyone waits for all 32 producers (sleepy poll, 1 thread/block) ---
    if (tid == 0) {
        while (__hip_atomic_load(done, __ATOMIC_RELAXED,
                                 __HIP_MEMORY_SCOPE_AGENT) < (unsigned)BATCH)
            __builtin_amdgcn_s_sleep(32);
    }
    __syncthreads();
    __builtin_amdgcn_fence(__ATOMIC_ACQUIRE, "agent");

    if (bf) {
        // [R5-proven MFMA body] mfma_f32_16x16x32_bf16:
        //   A frag: lane holds A[lane&15][(lane>>4)*8 .. +8)
        //   B frag: lane holds C2[tv*16+(lane&15)][(lane>>4)*8 .. +8)
        //   D frag: col=lane&15, row=(lane>>4)*4+j   [m89-verified]
        if (tv >= NVT) return;
        const unsigned short* ubf = u3bf;
        const short8v a00 = *(const short8v*)(ubf + ( 0 + l15) * EMBED +  0 + lh * 8);
        const short8v a01 = *(const short8v*)(ubf + ( 0 + l15) * EMBED + 32 + lh * 8);
        const short8v a10 = *(const short8v*)(ubf + (16 + l15) * EMBED +  0 + lh * 8);
        const short8v a11 = *(const short8v*)(ubf + (16 + l15) * EMBED + 32 + lh * 8);

        f32x4 acc0 = {0.f, 0.f, 0.f, 0.f};
        f32x4 acc1 = {0.f, 0.f, 0.f, 0.f};
        acc0 = __builtin_amdgcn_mfma_f32_16x16x32_bf16(a00, b0, acc0, 0, 0, 0);
        acc0 = __builtin_amdgcn_mfma_f32_16x16x32_bf16(a01, b1, acc0, 0, 0, 0);
        acc1 = __builtin_amdgcn_mfma_f32_16x16x32_bf16(a10, b0, acc1, 0, 0, 0);
        acc1 = __builtin_amdgcn_mfma_f32_16x16x32_bf16(a11, b1, acc1, 0, 0, 0);

        unsigned short* ob = (unsigned short*)out;
        const int v = tv * 16 + l15;
#pragma unroll
        for (int j = 0; j < 4; ++j) {
            const int br = lh * 4 + j;
            __hip_bfloat16 h0 = __float2bfloat16(acc0[j]);
            ob[(size_t)br * VOCAB + v] = *(unsigned short*)&h0;
            __hip_bfloat16 h1 = __float2bfloat16(acc1[j]);
            ob[(size_t)(16 + br) * VOCAB + v] = *(unsigned short*)&h1;
        }
    } else {
        // fp32 fallback: R0-proven LDS-staged per-thread dot (may spill under
        // the 64-VGPR cap; correctness path only)
        if (blockIdx.x * 256 >= VOCAB) return;
        for (int i = tid; i < BATCH * EMBED; i += 256) su[i] = u3g[i];
        __syncthreads();
        const int v = blockIdx.x * 256 + tid;
        if (v >= VOCAB) return;

        const size_t c2_off = (size_t)2 * VOCAB * EMBED;
        float row[EMBED];
        const float4* rp = (const float4*)((const float*)Cbase + c2_off + (size_t)v * EMBED);
#pragma unroll
        for (int i = 0; i < 16; ++i) {
            float4 r = rp[i];
            row[i*4 + 0] = r.x; row[i*4 + 1] = r.y;
            row[i*4 + 2] = r.z; row[i*4 + 3] = r.w;
        }
        float* of = (float*)out;
#pragma unroll
        for (int bb = 0; bb < BATCH; ++bb) {
            const float4* sp = (const float4*)(su + bb * EMBED);
            float acc = 0.f;
#pragma unroll
            for (int e4 = 0; e4 < 16; ++e4) {
                float4 us = sp[e4];
                acc += row[e4*4+0]*us.x + row[e4*4+1]*us.y
                     + row[e4*4+2]*us.z + row[e4*4+3]*us.w;
            }
            of[(size_t)bb * VOCAB + v] = acc;
        }
    }
}

extern "C" void kernel_launch(void* const* d_in, const int* in_sizes, int n_in,
                              void* d_out, int out_size, void* d_ws, size_t ws_size,
                              hipStream_t stream)
{
    const int*  stories = (const int*)d_in[0];
    const int*  queries = (const int*)d_in[1];
    const void* A       = d_in[2];
    const void* C       = d_in[3];
    const void* enc     = d_in[4];

    float* mc_ws = (float*)d_ws;                 // [6400,64] f32
    float* u0g   = mc_ws + NSLOT * EMBED;        // [32,64] f32
    float* u3g   = u0g + BATCH * EMBED;          // [32,64] f32
    unsigned short* u3bf = (unsigned short*)(u3g + BATCH * EMBED);  // [32,64] bf16
    // done counter on its own 256B-aligned line past u3bf
    char* p = (char*)(u3bf + BATCH * EMBED);
    unsigned* done = (unsigned*)((((size_t)p + 255) / 256) * 256);

    const int nblocks = (NSLOT + BATCH) / 4;     // 1608

    // workspace is poisoned between iterations -> zero the 4 B counter
    hipMemsetAsync(done, 0, sizeof(unsigned), stream);

    k_gather<<<nblocks, 256, 0, stream>>>(stories, queries, A, C, enc, mc_ws, u0g);
    k_out2<<<NOUTB, 256, 0, stream>>>(mc_ws, u0g, u3g, u3bf, done, C, enc, d_out);
}

// Round 8
// 158.368 us; speedup vs baseline: 2.0894x; 1.7102x over previous
//
#include <hip/hip_runtime.h>
#include <hip/hip_bf16.h>

#define VOCAB 100000
#define EMBED 64
#define SENT  20
#define MEM   50
#define BATCH 32
#define HOPS  3

// 4 gather sets: t=0 -> A (m for hop0); t=1..3 -> C[t-1] (c for hop t-1, m for hop t).
// Exploits m_h == c_{h-1} (same table, same words, same encoding).
#define NSET  4
#define NSLOT (NSET * BATCH * MEM)   // 6400
#define NVT   (VOCAB / 16)           // 6250 vocab tiles (exact)
#define LDSW  72                     // ushort stride for out-tile staging (16B-aligned rows)

typedef __attribute__((ext_vector_type(8))) short short8v;  // 8 bf16 = 4 VGPR
typedef __attribute__((ext_vector_type(4))) float f32x4;

__device__ __forceinline__ float bfr(unsigned short x) {
    union { unsigned int u; float f; } cv;
    cv.u = ((unsigned int)x) << 16;
    return cv.f;
}

// Runtime dtype probe: enc row 19 (last) is exactly 1.0 everywhere.
// bf16 storage: dword 639 packs elements 1278,1279 = (1.0bf,1.0bf) = 0x3F803F80.
__device__ __forceinline__ bool is_bf16(const void* enc) {
    return ((const unsigned int*)enc)[639] == 0x3F803F80u;
}

template<bool BF>
__device__ __forceinline__ float ldT(const void* p, size_t idx) {
    if constexpr (BF) return bfr(((const unsigned short*)p)[idx]);
    else              return ((const float*)p)[idx];
}

__device__ __forceinline__ float wave_sum(float d) {
#pragma unroll
    for (int off = 32; off > 0; off >>= 1) d += __shfl_xor(d, off, 64);
    return d;
}

// ---- gather body, dtype hoisted: one slot per wave (full-width, 6432 waves) ----
template<bool BF>
__device__ __forceinline__ void gather_body(const int* __restrict__ stories,
                                            const int* __restrict__ queries,
                                            const void* __restrict__ A,
                                            const void* __restrict__ C,
                                            const void* __restrict__ enc,
                                            float* __restrict__ mc_ws,
                                            float* __restrict__ u0g)
{
    const int tid = threadIdx.x;
    const int e   = tid & 63;
    const int gw  = blockIdx.x * 4 + (tid >> 6);
    const size_t VE = (size_t)VOCAB * EMBED;

    float encr[SENT];
#pragma unroll
    for (int s = 0; s < SENT; ++s) encr[s] = ldT<BF>(enc, s * EMBED + e);

    if (gw < NSLOT) {
        const int t  = gw / (BATCH * MEM);
        const int bm = gw % (BATCH * MEM);
        const void* T   = (t == 0) ? A : C;
        const size_t to = (t == 0) ? 0 : (size_t)(t - 1) * VE;

        int wst = (e < SENT) ? stories[bm * SENT + e] : 0;
        float acc = 0.f;
#pragma unroll
        for (int s = 0; s < SENT; ++s) {
            int w = __shfl(wst, s, 64);
            acc += ldT<BF>(T, to + (size_t)w * EMBED + e) * encr[s];
        }
        mc_ws[gw * EMBED + e] = acc;
    } else if (gw < NSLOT + BATCH) {
        const int b = gw - NSLOT;
        int wq = (e < SENT) ? queries[b * SENT + e] : 0;
        float u = 0.f;
#pragma unroll
        for (int s = 0; s < SENT; ++s) {
            int w = __shfl(wq, s, 64);
            u += ldT<BF>(A, (size_t)w * EMBED + e) * encr[s];
        }
        u0g[b * EMBED + e] = u;
    }
}

__global__ __launch_bounds__(256) void k_gather(
    const int* __restrict__ stories,   // [32,50,20]
    const int* __restrict__ queries,   // [32,20]
    const void* __restrict__ A,        // [V,64]
    const void* __restrict__ C,        // [3,V,64]
    const void* __restrict__ enc,      // [20,64]
    float* __restrict__ mc_ws,         // [6400,64]
    float* __restrict__ u0g)           // [32,64]
{
    if (is_bf16(enc)) gather_body<true >(stories, queries, A, C, enc, mc_ws, u0g);
    else              gather_body<false>(stories, queries, A, C, enc, mc_ws, u0g);
}

// One block (256 thr = 4 waves) per batch. All 4 sets preloaded to LDS
// (52 KB, stride-65 pad: both row and column views conflict-free).
// 3-hop recurrence entirely from LDS.  [R0/R5-proven; + u3bf epilogue]
__global__ __launch_bounds__(256) void k_recur2(
    const float* __restrict__ mc_ws,   // [4,1600,64] = [t][b*50+mm][e]
    const float* __restrict__ u0g,
    float* __restrict__ u3g,           // [32,64] fp32
    unsigned short* __restrict__ u3bf) // [32,64] bf16 (for MFMA k_out path)
{
    const int b    = blockIdx.x;
    const int tid  = threadIdx.x;
    const int lane = tid & 63;
    const int widx = tid >> 6;

    __shared__ float mc[NSET][MEM][65];   // 52 KB
    __shared__ float uls[EMBED];
    __shared__ float ols[4][EMBED];

    // cooperative float4 load: 4 sets x 50 rows x 16 float4 = 3200 loads
    for (int idx = tid; idx < NSET * MEM * 16; idx += 256) {
        int t  = idx / (MEM * 16);
        int r  = idx % (MEM * 16);
        int mm = r >> 4;
        int e4 = r & 15;
        const float4 v = *(const float4*)(mc_ws +
            (((size_t)t * BATCH * MEM) + (size_t)b * MEM + mm) * EMBED + e4 * 4);
        mc[t][mm][e4 * 4 + 0] = v.x;
        mc[t][mm][e4 * 4 + 1] = v.y;
        mc[t][mm][e4 * 4 + 2] = v.z;
        mc[t][mm][e4 * 4 + 3] = v.w;
    }
    if (tid < EMBED) uls[tid] = u0g[b * EMBED + tid];
    __syncthreads();

    for (int hop = 0; hop < HOPS; ++hop) {
        // dot: lane mm computes <m[mm], u> from LDS (all waves redundantly)
        float d = 0.f;
        if (lane < MEM) {
#pragma unroll
            for (int e = 0; e < EMBED; ++e)
                d += mc[hop][lane][e] * uls[e];
        }
        // softmax over lanes 0..49 (in-lane, per wave)
        float x = (lane < MEM) ? d : -3.4e38f;
        float mx = x;
#pragma unroll
        for (int off = 32; off > 0; off >>= 1) mx = fmaxf(mx, __shfl_xor(mx, off, 64));
        float ex = (lane < MEM) ? __expf(x - mx) : 0.f;
        float sm = wave_sum(ex);
        float p = ex / sm;

        // weighted sum: wave w covers mm = 13w .. 13w+12 (w3: 39..49)
        float o = 0.f;
#pragma unroll
        for (int k = 0; k < 13; ++k) {
            int mm = widx * 13 + k;
            if (mm < MEM)
                o += __shfl(p, mm, 64) * mc[hop + 1][mm][lane];
        }
        ols[widx][lane] = o;
        __syncthreads();
        if (tid < EMBED)
            uls[tid] += ols[0][tid] + ols[1][tid] + ols[2][tid] + ols[3][tid];
        __syncthreads();
    }

    if (tid < EMBED) {
        float uv = uls[tid];
        u3g[b * EMBED + tid] = uv;
        __hip_bfloat16 h = __float2bfloat16(uv);
        u3bf[b * EMBED + tid] = *(unsigned short*)&h;
    }
}

// ---- k_out bf16: MFMA tile GEMM  out[32 x 100000] = u3bf[32x64] . C2^T ----
// [R5-proven MFMA math] + LDS-staged coalesced stores (R7 counter evidence:
// direct 2B scatter stores inflated WRITE_SIZE 9x; stage 32x64 tile in LDS,
// write back 16B/thread -> every 64B line written once, full).
//   A frag: lane holds A[lane&15][(lane>>4)*8 .. +8)
//   B frag: lane holds C2[tv*16+(lane&15)][(lane>>4)*8 .. +8)
//   D frag: col=lane&15, row=(lane>>4)*4+j   [m89-verified]
__device__ __forceinline__ void out_mfma(const unsigned short* __restrict__ ubf,
                                         const void* __restrict__ Cbase,
                                         void* __restrict__ out,
                                         unsigned short* __restrict__ st) // [32][LDSW]
{
    const int tid  = threadIdx.x;
    const int w    = tid >> 6;
    const int tv   = blockIdx.x * 4 + w;
    const int lane = tid & 63;
    const int l15  = lane & 15;
    const int lh   = lane >> 4;

    const unsigned short* c2 =
        (const unsigned short*)Cbase + (size_t)2 * VOCAB * EMBED;

    if (tv < NVT) {
        const short8v a00 = *(const short8v*)(ubf + ( 0 + l15) * EMBED +  0 + lh * 8);
        const short8v a01 = *(const short8v*)(ubf + ( 0 + l15) * EMBED + 32 + lh * 8);
        const short8v a10 = *(const short8v*)(ubf + (16 + l15) * EMBED +  0 + lh * 8);
        const short8v a11 = *(const short8v*)(ubf + (16 + l15) * EMBED + 32 + lh * 8);

        const unsigned short* brow = c2 + ((size_t)tv * 16 + l15) * EMBED + lh * 8;
        const short8v b0 = *(const short8v*)(brow);
        const short8v b1 = *(const short8v*)(brow + 32);

        f32x4 acc0 = {0.f, 0.f, 0.f, 0.f};
        f32x4 acc1 = {0.f, 0.f, 0.f, 0.f};
        acc0 = __builtin_amdgcn_mfma_f32_16x16x32_bf16(a00, b0, acc0, 0, 0, 0);
        acc0 = __builtin_amdgcn_mfma_f32_16x16x32_bf16(a01, b1, acc0, 0, 0, 0);
        acc1 = __builtin_amdgcn_mfma_f32_16x16x32_bf16(a10, b0, acc1, 0, 0, 0);
        acc1 = __builtin_amdgcn_mfma_f32_16x16x32_bf16(a11, b1, acc1, 0, 0, 0);

        // stage into the block's 32x64 tile: col-in-block = w*16 + l15
        const int cb = w * 16 + l15;
#pragma unroll
        for (int j = 0; j < 4; ++j) {
            const int br = lh * 4 + j;
            __hip_bfloat16 h0 = __float2bfloat16(acc0[j]);
            st[br * LDSW + cb] = *(unsigned short*)&h0;
            __hip_bfloat16 h1 = __float2bfloat16(acc1[j]);
            st[(16 + br) * LDSW + cb] = *(unsigned short*)&h1;
        }
    }
    __syncthreads();

    // coalesced write-back: thread t -> row t>>3, 8-col segment t&7 (16 B)
    const int row  = tid >> 3;
    const int seg  = tid & 7;
    const int col0 = blockIdx.x * 64 + seg * 8;
    if (col0 < VOCAB) {   // VOCAB % 8 == 0 -> segment fully valid or fully not
        const uint4 vv = *(const uint4*)(st + row * LDSW + seg * 8);
        *(uint4*)((unsigned short*)out + (size_t)row * VOCAB + col0) = vv;
    }
}

// ---- k_out fp32 fallback: R0-proven LDS-staged per-thread dot ----
__device__ __forceinline__ void out_f32(const float* __restrict__ u,
                                        const void* __restrict__ Cbase,
                                        void* __restrict__ out,
                                        float* __restrict__ su)  // [BATCH*EMBED]
{
    if (blockIdx.x * 256 >= VOCAB) return;
    for (int i = threadIdx.x; i < BATCH * EMBED; i += 256) su[i] = u[i];
    __syncthreads();
    const int v = blockIdx.x * 256 + threadIdx.x;
    if (v >= VOCAB) return;

    const size_t c2_off = (size_t)2 * VOCAB * EMBED;
    float row[EMBED];
    const float4* rp = (const float4*)((const float*)Cbase + c2_off + (size_t)v * EMBED);
#pragma unroll
    for (int i = 0; i < 16; ++i) {
        float4 r = rp[i];
        row[i*4 + 0] = r.x; row[i*4 + 1] = r.y;
        row[i*4 + 2] = r.z; row[i*4 + 3] = r.w;
    }

    float* of = (float*)out;
#pragma unroll
    for (int bb = 0; bb < BATCH; ++bb) {
        const float4* sp = (const float4*)(su + bb * EMBED);
        float acc = 0.f;
#pragma unroll
        for (int e4 = 0; e4 < 16; ++e4) {
            float4 us = sp[e4];
            acc += row[e4*4+0]*us.x + row[e4*4+1]*us.y
                 + row[e4*4+2]*us.z + row[e4*4+3]*us.w;
        }
        of[(size_t)bb * VOCAB + v] = acc;
    }
}

__global__ __launch_bounds__(256) void k_out(const float* __restrict__ u,
                                             const unsigned short* __restrict__ ubf,
                                             const void* __restrict__ Cbase,
                                             const void* __restrict__ enc,
                                             void* __restrict__ out)
{
    __shared__ __align__(16) unsigned short st[32 * LDSW];  // 4.5 KB (bf16 path)
    __shared__ __align__(16) float su[BATCH * EMBED];       // 8 KB (fp32 path)
    if (is_bf16(enc)) out_mfma(ubf, Cbase, out, st);
    else              out_f32(u, Cbase, out, su);
}

extern "C" void kernel_launch(void* const* d_in, const int* in_sizes, int n_in,
                              void* d_out, int out_size, void* d_ws, size_t ws_size,
                              hipStream_t stream)
{
    const int*  stories = (const int*)d_in[0];
    const int*  queries = (const int*)d_in[1];
    const void* A       = d_in[2];
    const void* C       = d_in[3];
    const void* enc     = d_in[4];

    float* mc_ws = (float*)d_ws;                 // [6400,64] f32
    float* u0g   = mc_ws + NSLOT * EMBED;        // [32,64] f32
    float* u3g   = u0g + BATCH * EMBED;          // [32,64] f32
    unsigned short* u3bf = (unsigned short*)(u3g + BATCH * EMBED);  // [32,64] bf16

    const int nblocks = (NSLOT + BATCH) / 4;     // 1608
    const int noutblk = (NVT + 3) / 4;           // 1563 (64 cols per block)

    k_gather<<<nblocks, 256, 0, stream>>>(stories, queries, A, C, enc, mc_ws, u0g);
    k_recur2<<<BATCH, 256, 0, stream>>>(mc_ws, u0g, u3g, u3bf);
    k_out<<<noutblk, 256, 0, stream>>>(u3g, u3bf, C, enc, d_out);
}